// Round 1
// baseline (189.026 us; speedup 1.0000x reference)
//
#include <hip/hip_runtime.h>
#include <math.h>

#define NB 4
#define LQ 512
#define LK 512
#define DM 512
#define NH 8
#define DQ 64
#define NL 8
#define QT 32          // q-rows per attn block
#define PSTR 520       // Ps row stride in shorts (260 dwords % 32 = 4 -> 2-way max)

typedef short bf16x8 __attribute__((ext_vector_type(8)));
typedef _Float16 f16x8 __attribute__((ext_vector_type(8)));
typedef _Float16 f16x2 __attribute__((ext_vector_type(2)));
typedef float f32x4 __attribute__((ext_vector_type(4)));

__device__ __forceinline__ unsigned short f2bf(float x) {
    unsigned u = __float_as_uint(x);
    u += 0x7fff + ((u >> 16) & 1);          // RNE
    return (unsigned short)(u >> 16);
}
__device__ __forceinline__ float bf2f(unsigned x) {
    return __uint_as_float(x << 16);
}
__device__ __forceinline__ unsigned short f2h(float x) {
    _Float16 h = (_Float16)x;               // v_cvt_f16_f32 (RNE)
    return __builtin_bit_cast(unsigned short, h);
}

// ---------------------------------------------------------------------------
// prep: fp32->bf16 conversion of q,k,w_q,w_k,w_v,w_h (y=0..5) + em/pad 9-bit
// pack (y=6).  Pure memory-bound, fully coalesced.  (unchanged)
// ---------------------------------------------------------------------------
__global__ __launch_bounds__(256) void prep_kernel(
        const float* __restrict__ q,  const float* __restrict__ k,
        const float* __restrict__ wq, const float* __restrict__ wk,
        const float* __restrict__ wv, const float* __restrict__ wh,
        const float* __restrict__ em, const float* __restrict__ pad,
        unsigned short* __restrict__ qb,  unsigned short* __restrict__ kb,
        unsigned short* __restrict__ wqb, unsigned short* __restrict__ wkb,
        unsigned short* __restrict__ wvb, unsigned short* __restrict__ whb,
        unsigned short* __restrict__ Pk) {
    const int tid = threadIdx.x;
    const int y = blockIdx.y;
    if (y < 6) {
        const float* s; unsigned short* d; int n;
        switch (y) {
            case 0: s = q;  d = qb;  n = NB * LQ * DM; break;
            case 1: s = k;  d = kb;  n = NB * LK * DM; break;
            case 2: s = wq; d = wqb; n = DM * DM; break;
            case 3: s = wk; d = wkb; n = DM * DM; break;
            case 4: s = wv; d = wvb; n = DM * DM; break;
            default: s = wh; d = whb; n = DM * DM; break;
        }
        const int i = blockIdx.x * 256 + tid;
        if (i * 8 >= n) return;
        const float4* sv = (const float4*)s;
        const float4 a = sv[2 * (size_t)i], b = sv[2 * (size_t)i + 1];
        uint4 o;
        o.x = (unsigned)f2bf(a.x) | ((unsigned)f2bf(a.y) << 16);
        o.y = (unsigned)f2bf(a.z) | ((unsigned)f2bf(a.w) << 16);
        o.z = (unsigned)f2bf(b.x) | ((unsigned)f2bf(b.y) << 16);
        o.w = (unsigned)f2bf(b.z) | ((unsigned)f2bf(b.w) << 16);
        *(uint4*)(d + (size_t)i * 8) = o;
    } else {
        if (blockIdx.x >= 512) return;
        const int row = blockIdx.x * 4 + (tid >> 6);      // bq row
        const int k0 = (tid & 63) * 8;
        const float* eb = em + ((size_t)row * LK + k0) * NL;
        const float4 pv0 = *(const float4*)(pad + (size_t)row * LK + k0);
        const float4 pv1 = *(const float4*)(pad + (size_t)row * LK + k0 + 4);
        const float pv[8] = {pv0.x, pv0.y, pv0.z, pv0.w, pv1.x, pv1.y, pv1.z, pv1.w};
        unsigned short outv[8];
#pragma unroll
        for (int kk = 0; kk < 8; ++kk) {
            const float4 v0 = *(const float4*)(eb + kk * 8);
            const float4 v1 = *(const float4*)(eb + kk * 8 + 4);
            unsigned b_ = 0;
            b_ |= (v0.x != 0.f) << 0; b_ |= (v0.y != 0.f) << 1;
            b_ |= (v0.z != 0.f) << 2; b_ |= (v0.w != 0.f) << 3;
            b_ |= (v1.x != 0.f) << 4; b_ |= (v1.y != 0.f) << 5;
            b_ |= (v1.z != 0.f) << 6; b_ |= (v1.w != 0.f) << 7;
            b_ |= (pv[kk] != 0.f) << 8;
            outv[kk] = (unsigned short)b_;
        }
        uint4 o;
        o.x = (unsigned)outv[0] | ((unsigned)outv[1] << 16);
        o.y = (unsigned)outv[2] | ((unsigned)outv[3] << 16);
        o.z = (unsigned)outv[4] | ((unsigned)outv[5] << 16);
        o.w = (unsigned)outv[6] | ((unsigned)outv[7] << 16);
        *(uint4*)(Pk + (size_t)row * LK + k0) = o;
    }
}

// ---------------------------------------------------------------------------
// Input projections, direct-global MFMA fragments (A/B panels are L2-resident
// at these sizes; zero LDS, zero barriers).  z: 0=Q, 1=K, 2=V-transposed(f16).
// Fragment reads: 16 rows (l16) at 1KB stride x 4 quads x 16B = 16 full 64B
// lines per instruction -> fully coalesced.
// ---------------------------------------------------------------------------
__global__ __launch_bounds__(256) void proj_all(const unsigned short* __restrict__ qb,
                                                const unsigned short* __restrict__ kb,
                                                const unsigned short* __restrict__ wqb,
                                                const unsigned short* __restrict__ wkb,
                                                const unsigned short* __restrict__ wvb,
                                                const float* __restrict__ w_q_b,
                                                unsigned short* __restrict__ Qp,
                                                unsigned short* __restrict__ Kp,
                                                unsigned short* __restrict__ Vt) {
    const unsigned short* A; const unsigned short* W; const float* bias;
    unsigned short* C; int mode;
    switch (blockIdx.z) {
        case 0:  A = qb; W = wqb; bias = w_q_b;  C = Qp; mode = 0; break;
        case 1:  A = kb; W = wkb; bias = nullptr; C = Kp; mode = 0; break;
        default: A = kb; W = wvb; bias = nullptr; C = Vt; mode = 1; break;
    }
    const int tid = threadIdx.x, wave = tid >> 6, lane = tid & 63;
    const int quad = lane >> 4, l16 = lane & 15;
    const int wr = wave >> 1, wc = wave & 1;
    const int m0 = blockIdx.x * 64, n0 = blockIdx.y * 64;
    f32x4 acc[2][2];
    const f32x4 zz = {0.f, 0.f, 0.f, 0.f};
#pragma unroll
    for (int i = 0; i < 2; ++i)
#pragma unroll
        for (int j = 0; j < 2; ++j) acc[i][j] = zz;
    const unsigned short* Ar0 = A + (size_t)(m0 + wr * 32 + l16) * DM;
    const unsigned short* Ar1 = Ar0 + 16 * DM;
    const unsigned short* Br0 = W + (size_t)(n0 + wc * 32 + l16) * DM;
    const unsigned short* Br1 = Br0 + 16 * DM;
#pragma unroll 4
    for (int k0 = 0; k0 < DM; k0 += 32) {
        const int o = k0 + quad * 8;
        const bf16x8 a0 = *(const bf16x8*)&Ar0[o];
        const bf16x8 a1 = *(const bf16x8*)&Ar1[o];
        const bf16x8 b0 = *(const bf16x8*)&Br0[o];
        const bf16x8 b1 = *(const bf16x8*)&Br1[o];
        acc[0][0] = __builtin_amdgcn_mfma_f32_16x16x32_bf16(a0, b0, acc[0][0], 0, 0, 0);
        acc[0][1] = __builtin_amdgcn_mfma_f32_16x16x32_bf16(a0, b1, acc[0][1], 0, 0, 0);
        acc[1][0] = __builtin_amdgcn_mfma_f32_16x16x32_bf16(a1, b0, acc[1][0], 0, 0, 0);
        acc[1][1] = __builtin_amdgcn_mfma_f32_16x16x32_bf16(a1, b1, acc[1][1], 0, 0, 0);
    }
#pragma unroll
    for (int i = 0; i < 2; ++i)
#pragma unroll
        for (int r = 0; r < 4; ++r) {
            const int gm = m0 + wr * 32 + i * 16 + quad * 4 + r;
#pragma unroll
            for (int j = 0; j < 2; ++j) {
                const int gn = n0 + wc * 32 + j * 16 + l16;
                float v = acc[i][j][r];
                if (bias) v += bias[gn];
                if (mode == 0) C[(size_t)gm * DM + gn] = f2bf(v);
                else C[(size_t)(gm >> 9) * (DM * LK) + (size_t)gn * LK + (gm & 511)] = f2h(v);
            }
        }
}

// ---------------------------------------------------------------------------
// Fused attention per (z = h*4+b, 32-q-row tile).  512 thr = 8 waves.
// K/V/Q MFMA operands read DIRECTLY from global (64KB per-(b,h) slices are
// L2-resident, fragment reads touch 16 full cache lines per instruction).
// Only LDS use: Ps (attn tile, f16) for the register->A-fragment transpose,
// plus small reduction scratch.  5 barriers total (was ~20).
// rel-term via per-row nibble LUT; t-term via packed-f16 mask FMA.
// ---------------------------------------------------------------------------
__global__ __launch_bounds__(512, 4) void attn_fused(
        const unsigned short* __restrict__ Qp,
        const unsigned short* __restrict__ Kp,
        const unsigned short* __restrict__ Vt,     // f16
        const unsigned short* __restrict__ Pk,
        const float* __restrict__ b_ks,
        const float* __restrict__ b_vs,
        float* __restrict__ weights,
        unsigned short* __restrict__ Hb) {
    __shared__ __align__(16) short Ps[QT * PSTR]; // 32.5 KB attn f16
    __shared__ float svS[QT * NL];                // Q . b_ks
    __shared__ float lutS[QT * 32];               // nibble LUT: [row][lo16|hi16]
    __shared__ float tS[QT * NL];
    __shared__ float redA[QT * 8];                // per-wave-group max
    __shared__ float redB[QT * 8];                // per-wave-group sum

    const int tid = threadIdx.x, wave = tid >> 6, lane = tid & 63;
    const int quad = lane >> 4, l16 = lane & 15;
    const int q0 = blockIdx.x * QT;
    const int z = blockIdx.y, h = z >> 2, b = z & 3;

    // ---- svS[row][l] = sum_d Q[row][d] * b_ks[l][d], direct from global ----
    {
        const int row = tid >> 4, l = (tid >> 1) & 7, half = tid & 1;
        const unsigned short* qrow = Qp + (size_t)(b * LQ + q0 + row) * DM + h * DQ + half * 32;
        const float* bk = b_ks + l * DQ + half * 32;
        float s = 0.f;
#pragma unroll
        for (int d0 = 0; d0 < 32; d0 += 8) {
            const bf16x8 qv = *(const bf16x8*)&qrow[d0];
#pragma unroll
            for (int j = 0; j < 8; ++j)
                s = fmaf(bf2f((unsigned short)qv[j]), bk[d0 + j], s);
        }
        s += __shfl_xor(s, 1, 64);
        if (half == 0) svS[row * 8 + l] = s;
    }
    __syncthreads();                              // svS ready

    // ---- nibble LUT: rel = lut[row][w&15] + lut[row][16 + ((w>>4)&15)] ----
    for (int e = tid; e < QT * 32; e += 512) {
        const int row = e >> 5, idx = e & 31;
        const float* s = &svS[row * 8 + ((idx & 16) ? 4 : 0)];
        float v = 0.f;
        v += (idx & 1) ? s[0] : 0.f;
        v += (idx & 2) ? s[1] : 0.f;
        v += (idx & 4) ? s[2] : 0.f;
        v += (idx & 8) ? s[3] : 0.f;
        lutS[e] = v;
    }

    // ---- QK^T: S[32 x 512], operands straight from global (L2-hot) ----
    f32x4 acc[4][2];
    const f32x4 zz = {0.f, 0.f, 0.f, 0.f};
#pragma unroll
    for (int c = 0; c < 4; ++c) { acc[c][0] = zz; acc[c][1] = zz; }
    bf16x8 qf[2][2];
#pragma unroll
    for (int i = 0; i < 2; ++i)
#pragma unroll
        for (int kd = 0; kd < 2; ++kd)
            qf[i][kd] = *(const bf16x8*)&Qp[(size_t)(b * LQ + q0 + i * 16 + l16) * DM
                                           + h * DQ + kd * 32 + quad * 8];
#pragma unroll
    for (int c = 0; c < 4; ++c) {
        const unsigned short* krow = Kp + (size_t)(b * LK + c * 128 + wave * 16 + l16) * DM + h * DQ;
#pragma unroll
        for (int kd = 0; kd < 2; ++kd) {
            const bf16x8 bfv = *(const bf16x8*)&krow[kd * 32 + quad * 8];
#pragma unroll
            for (int i = 0; i < 2; ++i)
                acc[c][i] = __builtin_amdgcn_mfma_f32_16x16x32_bf16(qf[i][kd], bfv, acc[c][i], 0, 0, 0);
        }
    }
    __syncthreads();                              // lutS ready

    // ---- pass A: rel + mask + weights write + per-wave-group (max,sum) ----
#pragma unroll
    for (int i = 0; i < 2; ++i)
#pragma unroll
        for (int r = 0; r < 4; ++r) {
            const int row = i * 16 + quad * 4 + r;
            const int gq = q0 + row;
            const float* lrow = &lutS[row * 32];
            const unsigned short* prow = Pk + (size_t)(b * LQ + gq) * LK;
            float* wrow = weights + ((size_t)z * LQ + gq) * LK;
            float pm = -__builtin_inff();
#pragma unroll
            for (int c = 0; c < 4; ++c) {
                const int col = c * 128 + wave * 16 + l16;
                const unsigned w_ = prow[col];
                const float rel = lrow[w_ & 15u] + lrow[16 + ((w_ >> 4) & 15u)];
                const float wv = (acc[c][i][r] + rel) * 0.125f;
                wrow[col] = wv;                               // pre-mask weights
                const float m = ((w_ & 0x1FFu) == 0x100u) ? -__builtin_inff() : wv;
                acc[c][i][r] = m;
                pm = fmaxf(pm, m);
            }
#pragma unroll
            for (int o = 1; o < 16; o <<= 1) pm = fmaxf(pm, __shfl_xor(pm, o, 64));
            float ps = 0.f;
#pragma unroll
            for (int c = 0; c < 4; ++c) {
                const float e = __expf(acc[c][i][r] - pm);    // masked -> 0
                acc[c][i][r] = e;
                ps += e;
            }
#pragma unroll
            for (int o = 1; o < 16; o <<= 1) ps += __shfl_xor(ps, o, 64);
            if (l16 == 0) { redA[row * 8 + wave] = pm; redB[row * 8 + wave] = ps; }
        }
    __syncthreads();

    // ---- pass B: merge across 8 wave-groups, normalize, write Ps (f16) ----
#pragma unroll
    for (int i = 0; i < 2; ++i)
#pragma unroll
        for (int r = 0; r < 4; ++r) {
            const int row = i * 16 + quad * 4 + r;
            const f32x4 pa = *(const f32x4*)&redA[row * 8];
            const f32x4 pb = *(const f32x4*)&redA[row * 8 + 4];
            const f32x4 sa = *(const f32x4*)&redB[row * 8];
            const f32x4 sb = *(const f32x4*)&redB[row * 8 + 4];
            const float M = fmaxf(fmaxf(fmaxf(pa[0], pa[1]), fmaxf(pa[2], pa[3])),
                                  fmaxf(fmaxf(pb[0], pb[1]), fmaxf(pb[2], pb[3])));
            const float S = sa[0] * __expf(pa[0] - M) + sa[1] * __expf(pa[1] - M)
                          + sa[2] * __expf(pa[2] - M) + sa[3] * __expf(pa[3] - M)
                          + sb[0] * __expf(pb[0] - M) + sb[1] * __expf(pb[1] - M)
                          + sb[2] * __expf(pb[2] - M) + sb[3] * __expf(pb[3] - M);
            const float own = redA[row * 8 + wave];
            const float alpha = __expf(own - M) / S;
#pragma unroll
            for (int c = 0; c < 4; ++c) {
                const int col = c * 128 + wave * 16 + l16;
                Ps[row * PSTR + col] = (short)f2h(acc[c][i][r] * alpha);
            }
        }
    __syncthreads();   // Ps visible

    // ---- t[q][l] = sum_k attn * em_bit_l, packed-f16 mask FMA ----
    {
        const int row = tid >> 4, l = (tid >> 1) & 7, half = tid & 1;
        const uint4* pw = (const uint4*)(Pk + (size_t)(b * LQ + q0 + row) * LK + half * 256);
        const uint4* aw = (const uint4*)&Ps[row * PSTR + half * 256];
        float tv = 0.f;
#pragma unroll 4
        for (int kk = 0; kk < 32; ++kk) {
            const uint4 wb = pw[kk];
            const uint4 av = aw[kk];
            const unsigned w4[4] = {wb.x, wb.y, wb.z, wb.w};
            const unsigned a4[4] = {av.x, av.y, av.z, av.w};
            f16x2 hacc = {(_Float16)0.f, (_Float16)0.f};
#pragma unroll
            for (int u = 0; u < 4; ++u) {
                const unsigned bits = (w4[u] >> l) & 0x10001u;  // bit l of lo/hi ushort
                const unsigned msk = bits * 0x3c00u;            // {1.0h|0, 1.0h|0}
                hacc += __builtin_bit_cast(f16x2, a4[u]) * __builtin_bit_cast(f16x2, msk);
            }
            tv += (float)hacc[0] + (float)hacc[1];
        }
        tv += __shfl_xor(tv, 1, 64);
        if (half == 0) tS[row * 8 + l] = tv;
    }

    // ---- PV: O[32 x 64] = attn(f16, LDS) @ V(f16, direct global) ----
    f32x4 oacc = zz;
    const int mi = wave & 1, ni = wave >> 1;
    const unsigned short* vrow = Vt + (size_t)(b * DM + h * DQ + ni * 16 + l16) * LK;
    const short* psrow = &Ps[(mi * 16 + l16) * PSTR];
#pragma unroll 4
    for (int kc = 0; kc < LK; kc += 32) {
        const f16x8 afv = *(const f16x8*)&psrow[kc + quad * 8];
        const f16x8 bfv = *(const f16x8*)&vrow[kc + quad * 8];
        oacc = __builtin_amdgcn_mfma_f32_16x16x32_f16(afv, bfv, oacc, 0, 0, 0);
    }
    __syncthreads();   // tS visible

    // ---- output epilogue: + qvr, store Hb bf16 ----
    const int gd = ni * 16 + l16;
    float bvv[NL];
#pragma unroll
    for (int l = 0; l < NL; ++l) bvv[l] = b_vs[l * DQ + gd];
#pragma unroll
    for (int r = 0; r < 4; ++r) {
        const int row = mi * 16 + quad * 4 + r;
        const float* tp = &tS[row * 8];
        float o = oacc[r];
#pragma unroll
        for (int l = 0; l < NL; ++l) o = fmaf(tp[l], bvv[l], o);
        Hb[(size_t)(b * LQ + q0 + row) * DM + h * DQ + gd] = f2bf(o);
    }
}

// ---------------------------------------------------------------------------
// Output projection: Hb(bf16) @ whb(bf16)^T + bias, fp32 store.  Direct-global
// fragments, no LDS, no barriers.  Grid (32,8).
// ---------------------------------------------------------------------------
__global__ __launch_bounds__(256) void outproj_mfma(const unsigned short* __restrict__ Hb,
                                                    const unsigned short* __restrict__ whb,
                                                    const float* __restrict__ bias,
                                                    float* __restrict__ C) {
    const int tid = threadIdx.x, wave = tid >> 6, lane = tid & 63;
    const int quad = lane >> 4, l16 = lane & 15;
    const int wr = wave >> 1, wc = wave & 1;
    const int m0 = blockIdx.x * 64, n0 = blockIdx.y * 64;
    f32x4 acc[2][2];
    const f32x4 zz = {0.f, 0.f, 0.f, 0.f};
#pragma unroll
    for (int i = 0; i < 2; ++i)
#pragma unroll
        for (int j = 0; j < 2; ++j) acc[i][j] = zz;
    const unsigned short* Ar0 = Hb + (size_t)(m0 + wr * 32 + l16) * DM;
    const unsigned short* Ar1 = Ar0 + 16 * DM;
    const unsigned short* Br0 = whb + (size_t)(n0 + wc * 32 + l16) * DM;
    const unsigned short* Br1 = Br0 + 16 * DM;
#pragma unroll 4
    for (int k0 = 0; k0 < DM; k0 += 32) {
        const int o = k0 + quad * 8;
        const bf16x8 a0 = *(const bf16x8*)&Ar0[o];
        const bf16x8 a1 = *(const bf16x8*)&Ar1[o];
        const bf16x8 b0 = *(const bf16x8*)&Br0[o];
        const bf16x8 b1 = *(const bf16x8*)&Br1[o];
        acc[0][0] = __builtin_amdgcn_mfma_f32_16x16x32_bf16(a0, b0, acc[0][0], 0, 0, 0);
        acc[0][1] = __builtin_amdgcn_mfma_f32_16x16x32_bf16(a0, b1, acc[0][1], 0, 0, 0);
        acc[1][0] = __builtin_amdgcn_mfma_f32_16x16x32_bf16(a1, b0, acc[1][0], 0, 0, 0);
        acc[1][1] = __builtin_amdgcn_mfma_f32_16x16x32_bf16(a1, b1, acc[1][1], 0, 0, 0);
    }
#pragma unroll
    for (int i = 0; i < 2; ++i)
#pragma unroll
        for (int r = 0; r < 4; ++r) {
            const int gm = m0 + wr * 32 + i * 16 + quad * 4 + r;
#pragma unroll
            for (int j = 0; j < 2; ++j) {
                const int gn = n0 + wc * 32 + j * 16 + l16;
                C[(size_t)gm * DM + gn] = acc[i][j][r] + bias[gn];
            }
        }
}

// ---------------------------------------------------------------------------
extern "C" void kernel_launch(void* const* d_in, const int* in_sizes, int n_in,
                              void* d_out, int out_size, void* d_ws, size_t ws_size,
                              hipStream_t stream) {
    const float* q     = (const float*)d_in[0];
    const float* k     = (const float*)d_in[1];
    const float* em    = (const float*)d_in[2];
    const float* pad   = (const float*)d_in[3];
    const float* w_q_w = (const float*)d_in[4];
    const float* w_q_b = (const float*)d_in[5];
    const float* w_k   = (const float*)d_in[6];
    const float* w_v   = (const float*)d_in[7];
    const float* w_h_w = (const float*)d_in[8];
    const float* w_h_b = (const float*)d_in[9];
    const float* b_ks  = (const float*)d_in[10];
    const float* b_vs  = (const float*)d_in[11];

    float* out     = (float*)d_out;                       // (B, LQ, DM) fp32
    float* weights = out + (size_t)NB * LQ * DM;          // (H*B, LQ, LK) fp32

    char* ws = (char*)d_ws;
    unsigned short* qb  = (unsigned short*)(ws + 0);          // 2 MB
    unsigned short* kb  = (unsigned short*)(ws + 2097152);    // 2 MB
    unsigned short* wqb = (unsigned short*)(ws + 4194304);    // 512 KB
    unsigned short* wkb = (unsigned short*)(ws + 4718592);
    unsigned short* wvb = (unsigned short*)(ws + 5242880);
    unsigned short* whb = (unsigned short*)(ws + 5767168);
    unsigned short* Qp  = (unsigned short*)(ws + 6291456);    // 2 MB bf16
    unsigned short* Kp  = (unsigned short*)(ws + 8388608);    // 2 MB bf16
    unsigned short* Vt  = (unsigned short*)(ws + 10485760);   // 2 MB f16 [b][d][k]
    unsigned short* Hb  = (unsigned short*)(ws + 12582912);   // 2 MB bf16
    unsigned short* Pk  = (unsigned short*)(ws + 14680064);   // 2 MB 9-bit packs

    prep_kernel<<<dim3(1024, 7), 256, 0, stream>>>(q, k, w_q_w, w_k, w_v, w_h_w,
                                                   em, pad, qb, kb, wqb, wkb, wvb, whb, Pk);
    proj_all<<<dim3(32, 8, 3), 256, 0, stream>>>(qb, kb, wqb, wkb, wvb, w_q_b, Qp, Kp, Vt);
    attn_fused<<<dim3(LQ / QT, 32), 512, 0, stream>>>(Qp, Kp, Vt, Pk, b_ks, b_vs, weights, Hb);
    outproj_mfma<<<dim3(32, 8), 256, 0, stream>>>(Hb, whb, w_h_b, out);
}

// Round 2
// 168.135 us; speedup vs baseline: 1.1243x; 1.1243x over previous
//
#include <hip/hip_runtime.h>
#include <math.h>

#define NB 4
#define LQ 512
#define LK 512
#define DM 512
#define NH 8
#define DQ 64
#define NL 8
#define QT 32          // q-rows per attn block
#define PSTR 520       // Ps row stride in shorts (260 dwords % 32 = 4 -> 2-way max)

typedef short bf16x8 __attribute__((ext_vector_type(8)));
typedef _Float16 f16x8 __attribute__((ext_vector_type(8)));
typedef _Float16 f16x2 __attribute__((ext_vector_type(2)));
typedef float f32x4 __attribute__((ext_vector_type(4)));

__device__ __forceinline__ unsigned short f2bf(float x) {
    unsigned u = __float_as_uint(x);
    u += 0x7fff + ((u >> 16) & 1);          // RNE
    return (unsigned short)(u >> 16);
}
__device__ __forceinline__ float bf2f(unsigned x) {
    return __uint_as_float(x << 16);
}
__device__ __forceinline__ unsigned short f2h(float x) {
    _Float16 h = (_Float16)x;               // v_cvt_f16_f32 (RNE)
    return __builtin_bit_cast(unsigned short, h);
}
// async global->LDS, 16B/lane; LDS dest = wave-uniform base + lane*16
__device__ __forceinline__ void gld16(const void* g, void* l) {
    __builtin_amdgcn_global_load_lds(
        (const __attribute__((address_space(1))) void*)g,
        (__attribute__((address_space(3))) void*)l, 16, 0, 0);
}

// ---------------------------------------------------------------------------
// prep: fp32->bf16 conversion of q,k,w_q,w_k,w_v,w_h (y=0..5) + em/pad 9-bit
// pack (y=6).  Pure memory-bound, fully coalesced.
// ---------------------------------------------------------------------------
__global__ __launch_bounds__(256) void prep_kernel(
        const float* __restrict__ q,  const float* __restrict__ k,
        const float* __restrict__ wq, const float* __restrict__ wk,
        const float* __restrict__ wv, const float* __restrict__ wh,
        const float* __restrict__ em, const float* __restrict__ pad,
        unsigned short* __restrict__ qb,  unsigned short* __restrict__ kb,
        unsigned short* __restrict__ wqb, unsigned short* __restrict__ wkb,
        unsigned short* __restrict__ wvb, unsigned short* __restrict__ whb,
        unsigned short* __restrict__ Pk) {
    const int tid = threadIdx.x;
    const int y = blockIdx.y;
    if (y < 6) {
        const float* s; unsigned short* d; int n;
        switch (y) {
            case 0: s = q;  d = qb;  n = NB * LQ * DM; break;
            case 1: s = k;  d = kb;  n = NB * LK * DM; break;
            case 2: s = wq; d = wqb; n = DM * DM; break;
            case 3: s = wk; d = wkb; n = DM * DM; break;
            case 4: s = wv; d = wvb; n = DM * DM; break;
            default: s = wh; d = whb; n = DM * DM; break;
        }
        const int i = blockIdx.x * 256 + tid;
        if (i * 8 >= n) return;
        const float4* sv = (const float4*)s;
        const float4 a = sv[2 * (size_t)i], b = sv[2 * (size_t)i + 1];
        uint4 o;
        o.x = (unsigned)f2bf(a.x) | ((unsigned)f2bf(a.y) << 16);
        o.y = (unsigned)f2bf(a.z) | ((unsigned)f2bf(a.w) << 16);
        o.z = (unsigned)f2bf(b.x) | ((unsigned)f2bf(b.y) << 16);
        o.w = (unsigned)f2bf(b.z) | ((unsigned)f2bf(b.w) << 16);
        *(uint4*)(d + (size_t)i * 8) = o;
    } else {
        if (blockIdx.x >= 512) return;
        const int row = blockIdx.x * 4 + (tid >> 6);      // bq row
        const int k0 = (tid & 63) * 8;
        const float* eb = em + ((size_t)row * LK + k0) * NL;
        const float4 pv0 = *(const float4*)(pad + (size_t)row * LK + k0);
        const float4 pv1 = *(const float4*)(pad + (size_t)row * LK + k0 + 4);
        const float pv[8] = {pv0.x, pv0.y, pv0.z, pv0.w, pv1.x, pv1.y, pv1.z, pv1.w};
        unsigned short outv[8];
#pragma unroll
        for (int kk = 0; kk < 8; ++kk) {
            const float4 v0 = *(const float4*)(eb + kk * 8);
            const float4 v1 = *(const float4*)(eb + kk * 8 + 4);
            unsigned b_ = 0;
            b_ |= (v0.x != 0.f) << 0; b_ |= (v0.y != 0.f) << 1;
            b_ |= (v0.z != 0.f) << 2; b_ |= (v0.w != 0.f) << 3;
            b_ |= (v1.x != 0.f) << 4; b_ |= (v1.y != 0.f) << 5;
            b_ |= (v1.z != 0.f) << 6; b_ |= (v1.w != 0.f) << 7;
            b_ |= (pv[kk] != 0.f) << 8;
            outv[kk] = (unsigned short)b_;
        }
        uint4 o;
        o.x = (unsigned)outv[0] | ((unsigned)outv[1] << 16);
        o.y = (unsigned)outv[2] | ((unsigned)outv[3] << 16);
        o.z = (unsigned)outv[4] | ((unsigned)outv[5] << 16);
        o.w = (unsigned)outv[6] | ((unsigned)outv[7] << 16);
        *(uint4*)(Pk + (size_t)row * LK + k0) = o;
    }
}

// ---------------------------------------------------------------------------
// MFMA GEMM core: C(64x64) += A*B^T, BK=32.  LDS stride 32 shorts = 16 dwords
// -> 2-way max, no swizzle needed.  (round-0 structure: gld16 staging)
// ---------------------------------------------------------------------------
__device__ __forceinline__ void gemm64core(const unsigned short* __restrict__ Ag, int lda,
                                           const unsigned short* __restrict__ Bg, int ldb,
                                           int K, short* As, short* Bs,
                                           f32x4 (&acc)[2][2]) {
    const int tid = threadIdx.x;
    const int wave = tid >> 6, lane = tid & 63;
    const int quad = lane >> 4, l16 = lane & 15;
    const int wr = wave >> 1, wc = wave & 1;
    for (int k0 = 0; k0 < K; k0 += 32) {
        __syncthreads();
        gld16(Ag + (size_t)(tid >> 2) * lda + k0 + (tid & 3) * 8, (char*)As + wave * 1024);
        gld16(Bg + (size_t)(tid >> 2) * ldb + k0 + (tid & 3) * 8, (char*)Bs + wave * 1024);
        __syncthreads();
        bf16x8 af[2], bf[2];
#pragma unroll
        for (int i = 0; i < 2; ++i)
            af[i] = *(const bf16x8*)&As[(wr * 32 + i * 16 + l16) * 32 + quad * 8];
#pragma unroll
        for (int j = 0; j < 2; ++j)
            bf[j] = *(const bf16x8*)&Bs[(wc * 32 + j * 16 + l16) * 32 + quad * 8];
#pragma unroll
        for (int i = 0; i < 2; ++i)
#pragma unroll
            for (int j = 0; j < 2; ++j)
                acc[i][j] = __builtin_amdgcn_mfma_f32_16x16x32_bf16(af[i], bf[j], acc[i][j], 0, 0, 0);
    }
}

// ---------------------------------------------------------------------------
// Input projections, all-bf16 staging.  z: 0=Q, 1=K, 2=V-transposed (f16!).
// ---------------------------------------------------------------------------
__global__ __launch_bounds__(256) void proj_all(const unsigned short* __restrict__ qb,
                                                const unsigned short* __restrict__ kb,
                                                const unsigned short* __restrict__ wqb,
                                                const unsigned short* __restrict__ wkb,
                                                const unsigned short* __restrict__ wvb,
                                                const float* __restrict__ w_q_b,
                                                unsigned short* __restrict__ Qp,
                                                unsigned short* __restrict__ Kp,
                                                unsigned short* __restrict__ Vt) {
    __shared__ __align__(16) short As[64 * 32];
    __shared__ __align__(16) short Bs[64 * 32];
    const unsigned short* A; const unsigned short* W; const float* bias;
    unsigned short* C; int mode;
    switch (blockIdx.z) {
        case 0:  A = qb; W = wqb; bias = w_q_b;  C = Qp; mode = 0; break;
        case 1:  A = kb; W = wkb; bias = nullptr; C = Kp; mode = 0; break;
        default: A = kb; W = wvb; bias = nullptr; C = Vt; mode = 1; break;
    }
    f32x4 acc[2][2];
    const f32x4 zz = {0.f, 0.f, 0.f, 0.f};
#pragma unroll
    for (int i = 0; i < 2; ++i)
#pragma unroll
        for (int j = 0; j < 2; ++j) acc[i][j] = zz;
    const int m0 = blockIdx.x * 64, n0 = blockIdx.y * 64;
    gemm64core(A + (size_t)m0 * DM, DM, W + (size_t)n0 * DM, DM, DM, As, Bs, acc);
    const int tid = threadIdx.x, wave = tid >> 6, lane = tid & 63;
    const int quad = lane >> 4, l16 = lane & 15;
    const int wr = wave >> 1, wc = wave & 1;
#pragma unroll
    for (int i = 0; i < 2; ++i)
#pragma unroll
        for (int r = 0; r < 4; ++r) {
            const int gm = m0 + wr * 32 + i * 16 + quad * 4 + r;
#pragma unroll
            for (int j = 0; j < 2; ++j) {
                const int gn = n0 + wc * 32 + j * 16 + l16;
                float v = acc[i][j][r];
                if (bias) v += bias[gn];
                if (mode == 0) C[(size_t)gm * DM + gn] = f2bf(v);
                else C[(size_t)(gm >> 9) * (DM * LK) + (size_t)gn * LK + (gm & 511)] = f2h(v);
            }
        }
}

// ---------------------------------------------------------------------------
// Fused attention per (z = h*4+b, 32-q-row tile).  512 thr = 8 waves.
// Round-0 staged structure (gld16 + XOR-swizzled LDS tiles) with:
//  - vectorized svS from global (overlaps staging)
//  - nibble LUT for rel term
//  - Ps/V in f16, PV via f16 MFMA, packed-f16 t-pass
//  - Q fragments hoisted to registers once
// ---------------------------------------------------------------------------
__global__ __launch_bounds__(512, 4) void attn_fused(
        const unsigned short* __restrict__ Qp,
        const unsigned short* __restrict__ Kp,
        const unsigned short* __restrict__ Vt,     // f16 [b][d][k]
        const unsigned short* __restrict__ Pk,
        const float* __restrict__ b_ks,
        const float* __restrict__ b_vs,
        float* __restrict__ weights,
        unsigned short* __restrict__ Hb) {
    __shared__ __align__(16) short Qs[QT * 64];       // 4 KB   [q][d] swizzled
    __shared__ __align__(16) short Kc[128 * 64];      // 16 KB  K/V chunk swizzled
    __shared__ __align__(16) short Ps[QT * PSTR];     // 32.5 KB attn f16
    __shared__ float svS[QT * NL];
    __shared__ float lutS[QT * 32];                   // nibble LUT [row][lo16|hi16]
    __shared__ float tS[QT * NL];
    __shared__ float redA[QT * 8];                    // per-wave-group max
    __shared__ float redB[QT * 8];                    // per-wave-group sum

    const int tid = threadIdx.x, wave = tid >> 6, lane = tid & 63;
    const int quad = lane >> 4, l16 = lane & 15;
    const int q0 = blockIdx.x * QT;
    const int z = blockIdx.y, h = z >> 2, b = z & 3;

    // ---- stage Q tile (swizzled: slot chunk p holds global chunk p^(row&7))
    if (tid < 256) {
        const int row = tid >> 3, ch = tid & 7;
        gld16(Qp + (size_t)(b * LQ + q0 + row) * DM + h * DQ + ((ch ^ (row & 7)) * 8),
              (char*)Qs + wave * 1024);
    }

    // ---- svS[row][l] = sum_d Q[row][d] * b_ks[l][d], direct from global ----
    // (overlaps the async Q/K staging; Qp rows are L2-hot)
    {
        const int row = tid >> 4, l = (tid >> 1) & 7, half = tid & 1;
        const unsigned short* qrow = Qp + (size_t)(b * LQ + q0 + row) * DM + h * DQ + half * 32;
        const float* bk = b_ks + l * DQ + half * 32;
        float s = 0.f;
#pragma unroll
        for (int d0 = 0; d0 < 32; d0 += 8) {
            const bf16x8 qv = *(const bf16x8*)&qrow[d0];
#pragma unroll
            for (int j = 0; j < 8; ++j)
                s = fmaf(bf2f((unsigned short)qv[j]), bk[d0 + j], s);
        }
        s += __shfl_xor(s, 1, 64);
        if (half == 0) svS[row * 8 + l] = s;
    }

    // ---- QK^T: S[32 x 512] in 4 chunks of 128 k-rows ----
    f32x4 acc[4][2];
    const f32x4 zz = {0.f, 0.f, 0.f, 0.f};
#pragma unroll
    for (int c = 0; c < 4; ++c) { acc[c][0] = zz; acc[c][1] = zz; }
    bf16x8 qf[2][2];

    for (int c = 0; c < 4; ++c) {
#pragma unroll
        for (int it = 0; it < 2; ++it) {
            const int e = it * 512 + tid;
            const int kr = e >> 3, ch = e & 7;
            gld16(Kp + (size_t)(b * LK + c * 128 + kr) * DM + h * DQ + ((ch ^ (kr & 7)) * 8),
                  (char*)Kc + it * 8192 + wave * 1024);
        }
        __syncthreads();
        if (c == 0) {
            // hoist Q fragments out of the chunk loop (Qs now resident)
#pragma unroll
            for (int i = 0; i < 2; ++i)
#pragma unroll
                for (int kdi = 0; kdi < 2; ++kdi)
                    qf[i][kdi] = *(const bf16x8*)&Qs[(i * 16 + l16) * 64
                                                     + (((kdi * 4) + quad) ^ (l16 & 7)) * 8];
        }
#pragma unroll
        for (int kdi = 0; kdi < 2; ++kdi) {
            const int krow = wave * 16 + l16;
            const int kch = (kdi * 4 + quad) ^ (krow & 7);
            const bf16x8 bfv = *(const bf16x8*)&Kc[krow * 64 + kch * 8];
#pragma unroll
            for (int i = 0; i < 2; ++i)
                acc[c][i] = __builtin_amdgcn_mfma_f32_16x16x32_bf16(qf[i][kdi], bfv, acc[c][i], 0, 0, 0);
        }
        if (c == 0) {
            // nibble LUT: rel = lut[row][w&15] + lut[row][16+((w>>4)&15)]
            for (int e = tid; e < QT * 32; e += 512) {
                const int row = e >> 5, idx = e & 31;
                const float* s = &svS[row * 8 + ((idx & 16) ? 4 : 0)];
                float v = 0.f;
                v += (idx & 1) ? s[0] : 0.f;
                v += (idx & 2) ? s[1] : 0.f;
                v += (idx & 4) ? s[2] : 0.f;
                v += (idx & 8) ? s[3] : 0.f;
                lutS[e] = v;
            }
        }
        __syncthreads();
    }

    // ---- prefetch V chunk 0 into Kc (16-chunk rows, swizzle by row&15) ----
#pragma unroll
    for (int it = 0; it < 2; ++it) {
        const int e = it * 512 + tid;
        const int dd = e >> 4, ch = e & 15;
        gld16(Vt + (size_t)(b * DM + h * DQ + dd) * LK + ((ch ^ (dd & 15)) * 8),
              (char*)Kc + it * 8192 + wave * 1024);
    }

    // ---- pass A: rel + mask + weights write + per-wave-group (max,sum) ----
#pragma unroll
    for (int i = 0; i < 2; ++i)
#pragma unroll
        for (int r = 0; r < 4; ++r) {
            const int row = i * 16 + quad * 4 + r;
            const int gq = q0 + row;
            const float* lrow = &lutS[row * 32];
            const unsigned short* prow = Pk + (size_t)(b * LQ + gq) * LK;
            float* wrow = weights + ((size_t)z * LQ + gq) * LK;
            float pm = -__builtin_inff();
#pragma unroll
            for (int c = 0; c < 4; ++c) {
                const int col = c * 128 + wave * 16 + l16;
                const unsigned w_ = prow[col];
                const float rel = lrow[w_ & 15u] + lrow[16 + ((w_ >> 4) & 15u)];
                const float wv = (acc[c][i][r] + rel) * 0.125f;
                wrow[col] = wv;                               // pre-mask weights
                const float m = ((w_ & 0x1FFu) == 0x100u) ? -__builtin_inff() : wv;
                acc[c][i][r] = m;
                pm = fmaxf(pm, m);
            }
#pragma unroll
            for (int o = 1; o < 16; o <<= 1) pm = fmaxf(pm, __shfl_xor(pm, o, 64));
            float ps = 0.f;
#pragma unroll
            for (int c = 0; c < 4; ++c) {
                const float e = __expf(acc[c][i][r] - pm);    // masked -> 0
                acc[c][i][r] = e;
                ps += e;
            }
#pragma unroll
            for (int o = 1; o < 16; o <<= 1) ps += __shfl_xor(ps, o, 64);
            if (l16 == 0) { redA[row * 8 + wave] = pm; redB[row * 8 + wave] = ps; }
        }
    __syncthreads();

    // ---- pass B: online merge across 8 wave-groups, normalize, write Ps(f16)
#pragma unroll
    for (int i = 0; i < 2; ++i)
#pragma unroll
        for (int r = 0; r < 4; ++r) {
            const int row = i * 16 + quad * 4 + r;
            const f32x4 pa = *(const f32x4*)&redA[row * 8];
            const f32x4 pb = *(const f32x4*)&redA[row * 8 + 4];
            const f32x4 sa = *(const f32x4*)&redB[row * 8];
            const f32x4 sb = *(const f32x4*)&redB[row * 8 + 4];
            const float M = fmaxf(fmaxf(fmaxf(pa[0], pa[1]), fmaxf(pa[2], pa[3])),
                                  fmaxf(fmaxf(pb[0], pb[1]), fmaxf(pb[2], pb[3])));
            const float S = sa[0] * __expf(pa[0] - M) + sa[1] * __expf(pa[1] - M)
                          + sa[2] * __expf(pa[2] - M) + sa[3] * __expf(pa[3] - M)
                          + sb[0] * __expf(pb[0] - M) + sb[1] * __expf(pb[1] - M)
                          + sb[2] * __expf(pb[2] - M) + sb[3] * __expf(pb[3] - M);
            const float own = redA[row * 8 + wave];
            const float alpha = __expf(own - M) / S;
#pragma unroll
            for (int c = 0; c < 4; ++c) {
                const int col = c * 128 + wave * 16 + l16;
                Ps[row * PSTR + col] = (short)f2h(acc[c][i][r] * alpha);
            }
        }
    __syncthreads();   // Ps visible; V chunk 0 resident

    // ---- t[q][l] = sum_k attn * em_bit_l, packed-f16 mask FMA ----
    {
        const int row = tid >> 4, l = (tid >> 1) & 7, half = tid & 1;
        const uint4* pw = (const uint4*)(Pk + (size_t)(b * LQ + q0 + row) * LK + half * 256);
        const uint4* aw = (const uint4*)&Ps[row * PSTR + half * 256];
        float tv = 0.f;
#pragma unroll 4
        for (int kk = 0; kk < 32; ++kk) {
            const uint4 wb = pw[kk];
            const uint4 av = aw[kk];
            const unsigned w4[4] = {wb.x, wb.y, wb.z, wb.w};
            const unsigned a4[4] = {av.x, av.y, av.z, av.w};
            f16x2 hacc = {(_Float16)0.f, (_Float16)0.f};
#pragma unroll
            for (int u = 0; u < 4; ++u) {
                const unsigned bits = (w4[u] >> l) & 0x10001u;  // bit l of lo/hi ushort
                const unsigned msk = bits * 0x3c00u;            // {1.0h|0, 1.0h|0}
                hacc += __builtin_bit_cast(f16x2, a4[u]) * __builtin_bit_cast(f16x2, msk);
            }
            tv += (float)hacc[0] + (float)hacc[1];
        }
        tv += __shfl_xor(tv, 1, 64);
        if (half == 0) tS[row * 8 + l] = tv;
    }

    // ---- PV: O[32 x 64] = attn(f16) @ V(f16), V streamed in 4 chunks ----
    f32x4 oacc = zz;
    const int mi = wave & 1, ni = wave >> 1;
    for (int vc = 0; vc < 4; ++vc) {
        if (vc > 0) {
            __syncthreads();
#pragma unroll
            for (int it = 0; it < 2; ++it) {
                const int e = it * 512 + tid;
                const int dd = e >> 4, ch = e & 15;
                gld16(Vt + (size_t)(b * DM + h * DQ + dd) * LK + vc * 128 + ((ch ^ (dd & 15)) * 8),
                      (char*)Kc + it * 8192 + wave * 1024);
            }
            __syncthreads();
        }
#pragma unroll
        for (int kd = 0; kd < 128; kd += 32) {
            const int vrow = ni * 16 + l16;
            const int vch = ((kd >> 3) + quad) ^ (vrow & 15);
            const f16x8 afv = *(const f16x8*)&Ps[(mi * 16 + l16) * PSTR + vc * 128 + kd + quad * 8];
            const f16x8 bfv = *(const f16x8*)&Kc[vrow * 128 + vch * 8];
            oacc = __builtin_amdgcn_mfma_f32_16x16x32_f16(afv, bfv, oacc, 0, 0, 0);
        }
    }

    // ---- output epilogue: + qvr, store Hb bf16 ----
    const int gd = ni * 16 + l16;
    float bvv[NL];
#pragma unroll
    for (int l = 0; l < NL; ++l) bvv[l] = b_vs[l * DQ + gd];
#pragma unroll
    for (int r = 0; r < 4; ++r) {
        const int row = mi * 16 + quad * 4 + r;
        const float* tp = &tS[row * 8];
        float o = oacc[r];
#pragma unroll
        for (int l = 0; l < NL; ++l) o = fmaf(tp[l], bvv[l], o);
        Hb[(size_t)(b * LQ + q0 + row) * DM + h * DQ + gd] = f2bf(o);
    }
}

// ---------------------------------------------------------------------------
// Output projection: Hb(bf16) @ whb(bf16)^T + bias, fp32 store.  Grid (32,8).
// ---------------------------------------------------------------------------
__global__ __launch_bounds__(256) void outproj_mfma(const unsigned short* __restrict__ Hb,
                                                    const unsigned short* __restrict__ whb,
                                                    const float* __restrict__ bias,
                                                    float* __restrict__ C) {
    __shared__ __align__(16) short As[64 * 32];
    __shared__ __align__(16) short Bs[64 * 32];
    f32x4 acc[2][2];
    const f32x4 zz = {0.f, 0.f, 0.f, 0.f};
#pragma unroll
    for (int i = 0; i < 2; ++i)
#pragma unroll
        for (int j = 0; j < 2; ++j) acc[i][j] = zz;
    const int m0 = blockIdx.x * 64, n0 = blockIdx.y * 64;
    gemm64core(Hb + (size_t)m0 * DM, DM, whb + (size_t)n0 * DM, DM, DM, As, Bs, acc);
    const int tid = threadIdx.x, wave = tid >> 6, lane = tid & 63;
    const int quad = lane >> 4, l16 = lane & 15;
    const int wr = wave >> 1, wc = wave & 1;
#pragma unroll
    for (int i = 0; i < 2; ++i)
#pragma unroll
        for (int r = 0; r < 4; ++r) {
            const int gm = m0 + wr * 32 + i * 16 + quad * 4 + r;
#pragma unroll
            for (int j = 0; j < 2; ++j) {
                const int gn = n0 + wc * 32 + j * 16 + l16;
                C[(size_t)gm * DM + gn] = acc[i][j][r] + bias[gn];
            }
        }
}

// ---------------------------------------------------------------------------
extern "C" void kernel_launch(void* const* d_in, const int* in_sizes, int n_in,
                              void* d_out, int out_size, void* d_ws, size_t ws_size,
                              hipStream_t stream) {
    const float* q     = (const float*)d_in[0];
    const float* k     = (const float*)d_in[1];
    const float* em    = (const float*)d_in[2];
    const float* pad   = (const float*)d_in[3];
    const float* w_q_w = (const float*)d_in[4];
    const float* w_q_b = (const float*)d_in[5];
    const float* w_k   = (const float*)d_in[6];
    const float* w_v   = (const float*)d_in[7];
    const float* w_h_w = (const float*)d_in[8];
    const float* w_h_b = (const float*)d_in[9];
    const float* b_ks  = (const float*)d_in[10];
    const float* b_vs  = (const float*)d_in[11];

    float* out     = (float*)d_out;                       // (B, LQ, DM) fp32
    float* weights = out + (size_t)NB * LQ * DM;          // (H*B, LQ, LK) fp32

    char* ws = (char*)d_ws;
    unsigned short* qb  = (unsigned short*)(ws + 0);          // 2 MB
    unsigned short* kb  = (unsigned short*)(ws + 2097152);    // 2 MB
    unsigned short* wqb = (unsigned short*)(ws + 4194304);    // 512 KB
    unsigned short* wkb = (unsigned short*)(ws + 4718592);
    unsigned short* wvb = (unsigned short*)(ws + 5242880);
    unsigned short* whb = (unsigned short*)(ws + 5767168);
    unsigned short* Qp  = (unsigned short*)(ws + 6291456);    // 2 MB bf16
    unsigned short* Kp  = (unsigned short*)(ws + 8388608);    // 2 MB bf16
    unsigned short* Vt  = (unsigned short*)(ws + 10485760);   // 2 MB f16 [b][d][k]
    unsigned short* Hb  = (unsigned short*)(ws + 12582912);   // 2 MB bf16
    unsigned short* Pk  = (unsigned short*)(ws + 14680064);   // 2 MB 9-bit packs

    prep_kernel<<<dim3(1024, 7), 256, 0, stream>>>(q, k, w_q_w, w_k, w_v, w_h_w,
                                                   em, pad, qb, kb, wqb, wkb, wvb, whb, Pk);
    proj_all<<<dim3(32, 8, 3), 256, 0, stream>>>(qb, kb, wqb, wkb, wvb, w_q_b, Qp, Kp, Vt);
    attn_fused<<<dim3(LQ / QT, 32), 512, 0, stream>>>(Qp, Kp, Vt, Pk, b_ks, b_vs, weights, Hb);
    outproj_mfma<<<dim3(32, 8), 256, 0, stream>>>(Hb, whb, w_h_b, out);
}

// Round 3
// 166.628 us; speedup vs baseline: 1.1344x; 1.0090x over previous
//
#include <hip/hip_runtime.h>
#include <math.h>

#define NB 4
#define LQ 512
#define LK 512
#define DM 512
#define NH 8
#define DQ 64
#define NL 8
#define QT 32          // q-rows per attn block
#define PSTR 520       // Ps row stride in shorts (260 dwords % 32 = 4 -> 2-way max)

typedef short bf16x8 __attribute__((ext_vector_type(8)));
typedef _Float16 f16x8 __attribute__((ext_vector_type(8)));
typedef _Float16 f16x2 __attribute__((ext_vector_type(2)));
typedef float f32x4 __attribute__((ext_vector_type(4)));

__device__ __forceinline__ unsigned short f2bf(float x) {
    unsigned u = __float_as_uint(x);
    u += 0x7fff + ((u >> 16) & 1);          // RNE
    return (unsigned short)(u >> 16);
}
__device__ __forceinline__ float bf2f(unsigned x) {
    return __uint_as_float(x << 16);
}
__device__ __forceinline__ unsigned short f2h(float x) {
    _Float16 h = (_Float16)x;               // v_cvt_f16_f32 (RNE)
    return __builtin_bit_cast(unsigned short, h);
}
// async global->LDS, 16B/lane; LDS dest = wave-uniform base + lane*16
__device__ __forceinline__ void gld16(const void* g, void* l) {
    __builtin_amdgcn_global_load_lds(
        (const __attribute__((address_space(1))) void*)g,
        (__attribute__((address_space(3))) void*)l, 16, 0, 0);
}

// Counted-wait pipeline primitives (T3/T4).  WAITVM(N): wait until <=N vmem
// ops outstanding (gld16 LDS-write completion is tracked by vmcnt).  Raw
// s_barrier does NOT drain counters -> prefetched stages stay in flight.
#define WAITVM(N) asm volatile("s_waitcnt vmcnt(" #N ")" ::: "memory")
#define LGKM0()   asm volatile("s_waitcnt lgkmcnt(0)" ::: "memory")
#define BARR()    do { asm volatile("" ::: "memory"); \
                       __builtin_amdgcn_s_barrier();  \
                       asm volatile("" ::: "memory"); } while (0)

// ---------------------------------------------------------------------------
// prep: fp32->bf16 conversion of q,k,w_q,w_k,w_v,w_h (y=0..5) + em/pad 9-bit
// pack (y=6).  Pure memory-bound, fully coalesced.
// ---------------------------------------------------------------------------
__global__ __launch_bounds__(256) void prep_kernel(
        const float* __restrict__ q,  const float* __restrict__ k,
        const float* __restrict__ wq, const float* __restrict__ wk,
        const float* __restrict__ wv, const float* __restrict__ wh,
        const float* __restrict__ em, const float* __restrict__ pad,
        unsigned short* __restrict__ qb,  unsigned short* __restrict__ kb,
        unsigned short* __restrict__ wqb, unsigned short* __restrict__ wkb,
        unsigned short* __restrict__ wvb, unsigned short* __restrict__ whb,
        unsigned short* __restrict__ Pk) {
    const int tid = threadIdx.x;
    const int y = blockIdx.y;
    if (y < 6) {
        const float* s; unsigned short* d; int n;
        switch (y) {
            case 0: s = q;  d = qb;  n = NB * LQ * DM; break;
            case 1: s = k;  d = kb;  n = NB * LK * DM; break;
            case 2: s = wq; d = wqb; n = DM * DM; break;
            case 3: s = wk; d = wkb; n = DM * DM; break;
            case 4: s = wv; d = wvb; n = DM * DM; break;
            default: s = wh; d = whb; n = DM * DM; break;
        }
        const int i = blockIdx.x * 256 + tid;
        if (i * 8 >= n) return;
        const float4* sv = (const float4*)s;
        const float4 a = sv[2 * (size_t)i], b = sv[2 * (size_t)i + 1];
        uint4 o;
        o.x = (unsigned)f2bf(a.x) | ((unsigned)f2bf(a.y) << 16);
        o.y = (unsigned)f2bf(a.z) | ((unsigned)f2bf(a.w) << 16);
        o.z = (unsigned)f2bf(b.x) | ((unsigned)f2bf(b.y) << 16);
        o.w = (unsigned)f2bf(b.z) | ((unsigned)f2bf(b.w) << 16);
        *(uint4*)(d + (size_t)i * 8) = o;
    } else {
        const int row = blockIdx.x * 4 + (tid >> 6);      // bq row
        const int k0 = (tid & 63) * 8;
        const float* eb = em + ((size_t)row * LK + k0) * NL;
        const float4 pv0 = *(const float4*)(pad + (size_t)row * LK + k0);
        const float4 pv1 = *(const float4*)(pad + (size_t)row * LK + k0 + 4);
        const float pv[8] = {pv0.x, pv0.y, pv0.z, pv0.w, pv1.x, pv1.y, pv1.z, pv1.w};
        unsigned short outv[8];
#pragma unroll
        for (int kk = 0; kk < 8; ++kk) {
            const float4 v0 = *(const float4*)(eb + kk * 8);
            const float4 v1 = *(const float4*)(eb + kk * 8 + 4);
            unsigned b_ = 0;
            b_ |= (v0.x != 0.f) << 0; b_ |= (v0.y != 0.f) << 1;
            b_ |= (v0.z != 0.f) << 2; b_ |= (v0.w != 0.f) << 3;
            b_ |= (v1.x != 0.f) << 4; b_ |= (v1.y != 0.f) << 5;
            b_ |= (v1.z != 0.f) << 6; b_ |= (v1.w != 0.f) << 7;
            b_ |= (pv[kk] != 0.f) << 8;
            outv[kk] = (unsigned short)b_;
        }
        uint4 o;
        o.x = (unsigned)outv[0] | ((unsigned)outv[1] << 16);
        o.y = (unsigned)outv[2] | ((unsigned)outv[3] << 16);
        o.z = (unsigned)outv[4] | ((unsigned)outv[5] << 16);
        o.w = (unsigned)outv[6] | ((unsigned)outv[7] << 16);
        *(uint4*)(Pk + (size_t)row * LK + k0) = o;
    }
}

// ---------------------------------------------------------------------------
// MFMA GEMM core: C(64x64) += A*B^T, BK=32, DOUBLE-BUFFERED with counted
// vmcnt (T3/T4): stage s+1 is issued before waiting on stage s, so the
// global->LDS latency hides under the MFMA + barriers of the current step.
// As/Bs: [2][64*32] shorts (4KB halves).
// ---------------------------------------------------------------------------
__device__ __forceinline__ void gemm64core(const unsigned short* __restrict__ Ag, int lda,
                                           const unsigned short* __restrict__ Bg, int ldb,
                                           short* As, short* Bs,
                                           f32x4 (&acc)[2][2]) {
    const int tid = threadIdx.x;
    const int wave = tid >> 6, lane = tid & 63;
    const int quad = lane >> 4, l16 = lane & 15;
    const int wr = wave >> 1, wc = wave & 1;
    const int r_ = tid >> 2, c_ = (tid & 3) * 8;
    const unsigned short* Ar = Ag + (size_t)r_ * lda + c_;
    const unsigned short* Br = Bg + (size_t)r_ * ldb + c_;
    // prologue: stage step 0 into buffer 0
    gld16(Ar, (char*)As + wave * 1024);
    gld16(Br, (char*)Bs + wave * 1024);
#pragma unroll
    for (int s = 0; s < 16; ++s) {
        if (s < 15) {
            const int nb = (s + 1) & 1;
            gld16(Ar + (s + 1) * 32, (char*)As + nb * 4096 + wave * 1024);
            gld16(Br + (s + 1) * 32, (char*)Bs + nb * 4096 + wave * 1024);
            WAITVM(2);                 // step-s data in LDS; next stage in flight
        } else {
            WAITVM(0);
        }
        BARR();
        const int cb = s & 1;
        bf16x8 af[2], bf[2];
#pragma unroll
        for (int i = 0; i < 2; ++i)
            af[i] = *(const bf16x8*)&As[cb * 2048 + (wr * 32 + i * 16 + l16) * 32 + quad * 8];
#pragma unroll
        for (int j = 0; j < 2; ++j)
            bf[j] = *(const bf16x8*)&Bs[cb * 2048 + (wc * 32 + j * 16 + l16) * 32 + quad * 8];
#pragma unroll
        for (int i = 0; i < 2; ++i)
#pragma unroll
            for (int j = 0; j < 2; ++j)
                acc[i][j] = __builtin_amdgcn_mfma_f32_16x16x32_bf16(af[i], bf[j], acc[i][j], 0, 0, 0);
        BARR();                        // readers done -> buffer may be overwritten
    }
}

// ---------------------------------------------------------------------------
// Input projections, all-bf16 staging.  z: 0=Q, 1=K, 2=V-transposed (f16!).
// ---------------------------------------------------------------------------
__global__ __launch_bounds__(256) void proj_all(const unsigned short* __restrict__ qb,
                                                const unsigned short* __restrict__ kb,
                                                const unsigned short* __restrict__ wqb,
                                                const unsigned short* __restrict__ wkb,
                                                const unsigned short* __restrict__ wvb,
                                                const float* __restrict__ w_q_b,
                                                unsigned short* __restrict__ Qp,
                                                unsigned short* __restrict__ Kp,
                                                unsigned short* __restrict__ Vt) {
    __shared__ __align__(16) short As[2][64 * 32];
    __shared__ __align__(16) short Bs[2][64 * 32];
    const unsigned short* A; const unsigned short* W; const float* bias;
    unsigned short* C; int mode;
    switch (blockIdx.z) {
        case 0:  A = qb; W = wqb; bias = w_q_b;  C = Qp; mode = 0; break;
        case 1:  A = kb; W = wkb; bias = nullptr; C = Kp; mode = 0; break;
        default: A = kb; W = wvb; bias = nullptr; C = Vt; mode = 1; break;
    }
    f32x4 acc[2][2];
    const f32x4 zz = {0.f, 0.f, 0.f, 0.f};
#pragma unroll
    for (int i = 0; i < 2; ++i)
#pragma unroll
        for (int j = 0; j < 2; ++j) acc[i][j] = zz;
    const int m0 = blockIdx.x * 64, n0 = blockIdx.y * 64;
    gemm64core(A + (size_t)m0 * DM, DM, W + (size_t)n0 * DM, DM, &As[0][0], &Bs[0][0], acc);
    const int tid = threadIdx.x, wave = tid >> 6, lane = tid & 63;
    const int quad = lane >> 4, l16 = lane & 15;
    const int wr = wave >> 1, wc = wave & 1;
#pragma unroll
    for (int i = 0; i < 2; ++i)
#pragma unroll
        for (int r = 0; r < 4; ++r) {
            const int gm = m0 + wr * 32 + i * 16 + quad * 4 + r;
#pragma unroll
            for (int j = 0; j < 2; ++j) {
                const int gn = n0 + wc * 32 + j * 16 + l16;
                float v = acc[i][j][r];
                if (bias) v += bias[gn];
                if (mode == 0) C[(size_t)gm * DM + gn] = f2bf(v);
                else C[(size_t)(gm >> 9) * (DM * LK) + (size_t)gn * LK + (gm & 511)] = f2h(v);
            }
        }
}

// ---------------------------------------------------------------------------
// Fused attention per (z = h*4+b, 32-q-row tile).  512 thr = 8 waves.
// 8-slot staging pipeline (K0..K3, V0..V3) through a 2x16KB double buffer
// with counted vmcnt: every slot issues exactly 2 gld16 per wave, so
// WAITVM(2) = "previous slot landed, next slot still in flight".  Pass A/B
// and the t-pass overlap the V0/V1 staging latency.
// ---------------------------------------------------------------------------
#define STAGE_K(c, hb) do {                                                       \
    _Pragma("unroll")                                                             \
    for (int it_ = 0; it_ < 2; ++it_) {                                           \
        const int e_ = it_ * 512 + tid;                                           \
        const int kr_ = e_ >> 3, ch_ = e_ & 7;                                    \
        gld16(Kp + (size_t)(b * LK + (c) * 128 + kr_) * DM + h * DQ               \
                  + ((ch_ ^ (kr_ & 7)) * 8),                                      \
              (char*)&Kc[hb][0] + it_ * 8192 + wave * 1024);                      \
    } } while (0)

#define STAGE_V(vc, hb) do {                                                      \
    _Pragma("unroll")                                                             \
    for (int it_ = 0; it_ < 2; ++it_) {                                           \
        const int e_ = it_ * 512 + tid;                                           \
        const int dd_ = e_ >> 4, ch_ = e_ & 15;                                   \
        gld16(Vt + (size_t)(b * DM + h * DQ + dd_) * LK + (vc) * 128              \
                  + ((ch_ ^ (dd_ & 15)) * 8),                                     \
              (char*)&Kc[hb][0] + it_ * 8192 + wave * 1024);                      \
    } } while (0)

#define COMPUTE_K(c, hb) do {                                                     \
    _Pragma("unroll")                                                             \
    for (int kdi_ = 0; kdi_ < 2; ++kdi_) {                                        \
        const int krow_ = wave * 16 + l16;                                        \
        const int kch_ = (kdi_ * 4 + quad) ^ (krow_ & 7);                         \
        const bf16x8 bfv_ = *(const bf16x8*)&Kc[hb][krow_ * 64 + kch_ * 8];       \
        acc[c][0] = __builtin_amdgcn_mfma_f32_16x16x32_bf16(qf[0][kdi_], bfv_,    \
                                                            acc[c][0], 0, 0, 0); \
        acc[c][1] = __builtin_amdgcn_mfma_f32_16x16x32_bf16(qf[1][kdi_], bfv_,    \
                                                            acc[c][1], 0, 0, 0); \
    } } while (0)

#define COMPUTE_V(vc, hb) do {                                                    \
    _Pragma("unroll")                                                             \
    for (int kd_ = 0; kd_ < 128; kd_ += 32) {                                     \
        const int vrow_ = ni * 16 + l16;                                          \
        const int vch_ = ((kd_ >> 3) + quad) ^ (vrow_ & 15);                      \
        const f16x8 afv_ = *(const f16x8*)&Ps[(mi * 16 + l16) * PSTR              \
                                              + (vc) * 128 + kd_ + quad * 8];     \
        const f16x8 bfv_ = *(const f16x8*)&Kc[hb][vrow_ * 128 + vch_ * 8];        \
        oacc = __builtin_amdgcn_mfma_f32_16x16x32_f16(afv_, bfv_, oacc, 0, 0, 0); \
    } } while (0)

__global__ __launch_bounds__(512, 4) void attn_fused(
        const unsigned short* __restrict__ Qp,
        const unsigned short* __restrict__ Kp,
        const unsigned short* __restrict__ Vt,     // f16 [b][d][k]
        const unsigned short* __restrict__ Pk,
        const float* __restrict__ b_ks,
        const float* __restrict__ b_vs,
        float* __restrict__ weights,
        unsigned short* __restrict__ Hb) {
    __shared__ __align__(16) short Qs[QT * 64];       // 4 KB   [q][d] swizzled
    __shared__ __align__(16) short Kc[2][128 * 64];   // 32 KB  K/V double buffer
    __shared__ __align__(16) short Ps[QT * PSTR];     // 32.5 KB attn f16
    __shared__ float svS[QT * NL];
    __shared__ float lutS[QT * 32];                   // nibble LUT [row][lo16|hi16]
    __shared__ float tS[QT * NL];
    __shared__ float redA[QT * 8];                    // per-wave-group max
    __shared__ float redB[QT * 8];                    // per-wave-group sum

    const int tid = threadIdx.x, wave = tid >> 6, lane = tid & 63;
    const int quad = lane >> 4, l16 = lane & 15;
    const int q0 = blockIdx.x * QT;
    const int z = blockIdx.y, h = z >> 2, b = z & 3;

    // ---- svS source loads (issued before the stages in program order) ----
    const int srow = tid >> 4, sl = (tid >> 1) & 7, shalf = tid & 1;
    bf16x8 sq[4];
    {
        const unsigned short* qrow = Qp + (size_t)(b * LQ + q0 + srow) * DM + h * DQ + shalf * 32;
#pragma unroll
        for (int d0 = 0; d0 < 4; ++d0) sq[d0] = *(const bf16x8*)&qrow[d0 * 8];
    }

    // ---- stage Q tile (swizzled) + K0/K1 double-buffer prologue ----
    if (tid < 256) {
        const int row = tid >> 3, ch = tid & 7;
        gld16(Qp + (size_t)(b * LQ + q0 + row) * DM + h * DQ + ((ch ^ (row & 7)) * 8),
              (char*)Qs + wave * 1024);
    }
    STAGE_K(0, 0);
    STAGE_K(1, 1);

    // ---- svS[row][l] = sum_d Q[row][d] * b_ks[l][d] (register data) ----
    {
        const float* bk = b_ks + sl * DQ + shalf * 32;
        float s = 0.f;
#pragma unroll
        for (int d0 = 0; d0 < 4; ++d0)
#pragma unroll
            for (int j = 0; j < 8; ++j)
                s = fmaf(bf2f((unsigned short)sq[d0][j]), bk[d0 * 8 + j], s);
        s += __shfl_xor(s, 1, 64);
        if (shalf == 0) svS[srow * 8 + sl] = s;
    }

    f32x4 acc[4][2];
    const f32x4 zz = {0.f, 0.f, 0.f, 0.f};
#pragma unroll
    for (int c = 0; c < 4; ++c) { acc[c][0] = zz; acc[c][1] = zz; }
    bf16x8 qf[2][2];

    // ================= K pipeline =================
    // t=0: K0 ready (K1 in flight)
    WAITVM(2); LGKM0(); BARR();
#pragma unroll
    for (int i = 0; i < 2; ++i)
#pragma unroll
        for (int kdi = 0; kdi < 2; ++kdi)
            qf[i][kdi] = *(const bf16x8*)&Qs[(i * 16 + l16) * 64
                                             + (((kdi * 4) + quad) ^ (l16 & 7)) * 8];
    // nibble LUT from svS (visible since barrier)
#pragma unroll
    for (int e2 = 0; e2 < 2; ++e2) {
        const int e = e2 * 512 + tid;
        const int row = e >> 5, idx = e & 31;
        const float* sp = &svS[row * 8 + ((idx & 16) ? 4 : 0)];
        float v = 0.f;
        v += (idx & 1) ? sp[0] : 0.f;
        v += (idx & 2) ? sp[1] : 0.f;
        v += (idx & 4) ? sp[2] : 0.f;
        v += (idx & 8) ? sp[3] : 0.f;
        lutS[e] = v;
    }
    COMPUTE_K(0, 0);
    LGKM0(); BARR();
    STAGE_K(2, 0);
    // t=1
    WAITVM(2); LGKM0(); BARR();
    COMPUTE_K(1, 1);
    LGKM0(); BARR();
    STAGE_K(3, 1);
    // t=2
    WAITVM(2); LGKM0(); BARR();
    COMPUTE_K(2, 0);
    LGKM0(); BARR();
    STAGE_V(0, 0);
    // t=3
    WAITVM(2); LGKM0(); BARR();
    COMPUTE_K(3, 1);
    LGKM0(); BARR();
    STAGE_V(1, 1);
    // (V0/V1 staging latency now overlaps pass A / pass B / t-pass)

    // ---- pass A: rel + mask + weights write + per-wave-group (max,sum) ----
#pragma unroll
    for (int i = 0; i < 2; ++i)
#pragma unroll
        for (int r = 0; r < 4; ++r) {
            const int row = i * 16 + quad * 4 + r;
            const int gq = q0 + row;
            const float* lrow = &lutS[row * 32];
            const unsigned short* prow = Pk + (size_t)(b * LQ + gq) * LK;
            float* wrow = weights + ((size_t)z * LQ + gq) * LK;
            float pm = -__builtin_inff();
#pragma unroll
            for (int c = 0; c < 4; ++c) {
                const int col = c * 128 + wave * 16 + l16;
                const unsigned w_ = prow[col];
                const float rel = lrow[w_ & 15u] + lrow[16 + ((w_ >> 4) & 15u)];
                const float wv = (acc[c][i][r] + rel) * 0.125f;
                wrow[col] = wv;                               // pre-mask weights
                const float m = ((w_ & 0x1FFu) == 0x100u) ? -__builtin_inff() : wv;
                acc[c][i][r] = m;
                pm = fmaxf(pm, m);
            }
#pragma unroll
            for (int o = 1; o < 16; o <<= 1) pm = fmaxf(pm, __shfl_xor(pm, o, 64));
            float ps = 0.f;
#pragma unroll
            for (int c = 0; c < 4; ++c) {
                const float e = __expf(acc[c][i][r] - pm);    // masked -> 0
                acc[c][i][r] = e;
                ps += e;
            }
#pragma unroll
            for (int o = 1; o < 16; o <<= 1) ps += __shfl_xor(ps, o, 64);
            if (l16 == 0) { redA[row * 8 + wave] = pm; redB[row * 8 + wave] = ps; }
        }
    LGKM0(); BARR();

    // ---- pass B: merge across 8 wave-groups, normalize, write Ps (f16) ----
#pragma unroll
    for (int i = 0; i < 2; ++i)
#pragma unroll
        for (int r = 0; r < 4; ++r) {
            const int row = i * 16 + quad * 4 + r;
            const f32x4 pa = *(const f32x4*)&redA[row * 8];
            const f32x4 pb = *(const f32x4*)&redA[row * 8 + 4];
            const f32x4 sa = *(const f32x4*)&redB[row * 8];
            const f32x4 sb = *(const f32x4*)&redB[row * 8 + 4];
            const float M = fmaxf(fmaxf(fmaxf(pa[0], pa[1]), fmaxf(pa[2], pa[3])),
                                  fmaxf(fmaxf(pb[0], pb[1]), fmaxf(pb[2], pb[3])));
            const float S = sa[0] * __expf(pa[0] - M) + sa[1] * __expf(pa[1] - M)
                          + sa[2] * __expf(pa[2] - M) + sa[3] * __expf(pa[3] - M)
                          + sb[0] * __expf(pb[0] - M) + sb[1] * __expf(pb[1] - M)
                          + sb[2] * __expf(pb[2] - M) + sb[3] * __expf(pb[3] - M);
            const float own = redA[row * 8 + wave];
            const float alpha = __expf(own - M) / S;
#pragma unroll
            for (int c = 0; c < 4; ++c) {
                const int col = c * 128 + wave * 16 + l16;
                Ps[row * PSTR + col] = (short)f2h(acc[c][i][r] * alpha);
            }
        }
    LGKM0(); BARR();   // Ps visible

    // ---- t[q][l] = sum_k attn * em_bit_l, packed-f16 mask FMA ----
    {
        const int row = tid >> 4, l = (tid >> 1) & 7, half = tid & 1;
        const uint4* pw = (const uint4*)(Pk + (size_t)(b * LQ + q0 + row) * LK + half * 256);
        const uint4* aw = (const uint4*)&Ps[row * PSTR + half * 256];
        float tv = 0.f;
#pragma unroll 4
        for (int kk = 0; kk < 32; ++kk) {
            const uint4 wb = pw[kk];
            const uint4 av = aw[kk];
            const unsigned w4[4] = {wb.x, wb.y, wb.z, wb.w};
            const unsigned a4[4] = {av.x, av.y, av.z, av.w};
            f16x2 hacc = {(_Float16)0.f, (_Float16)0.f};
#pragma unroll
            for (int u = 0; u < 4; ++u) {
                const unsigned bits = (w4[u] >> l) & 0x10001u;  // bit l of lo/hi ushort
                const unsigned msk = bits * 0x3c00u;            // {1.0h|0, 1.0h|0}
                hacc += __builtin_bit_cast(f16x2, a4[u]) * __builtin_bit_cast(f16x2, msk);
            }
            tv += (float)hacc[0] + (float)hacc[1];
        }
        tv += __shfl_xor(tv, 1, 64);
        if (half == 0) tS[row * 8 + l] = tv;
    }

    // ================= V pipeline =================
    f32x4 oacc = zz;
    const int mi = wave & 1, ni = wave >> 1;
    // t=4: V0 (staged long ago; drain everything once, incl. weight stores)
    WAITVM(0); LGKM0(); BARR();
    COMPUTE_V(0, 0);
    BARR();
    STAGE_V(2, 0);
    // t=5
    WAITVM(2); LGKM0(); BARR();
    COMPUTE_V(1, 1);
    BARR();
    STAGE_V(3, 1);
    // t=6
    WAITVM(2); LGKM0(); BARR();
    COMPUTE_V(2, 0);
    // t=7 (no stage follows; single ready-transition)
    WAITVM(0); LGKM0(); BARR();
    COMPUTE_V(3, 1);

    // ---- output epilogue: + qvr, store Hb bf16 (tS visible since t=4 barrier)
    const int gd = ni * 16 + l16;
    float bvv[NL];
#pragma unroll
    for (int l = 0; l < NL; ++l) bvv[l] = b_vs[l * DQ + gd];
#pragma unroll
    for (int r = 0; r < 4; ++r) {
        const int row = mi * 16 + quad * 4 + r;
        const float* tp = &tS[row * 8];
        float o = oacc[r];
#pragma unroll
        for (int l = 0; l < NL; ++l) o = fmaf(tp[l], bvv[l], o);
        Hb[(size_t)(b * LQ + q0 + row) * DM + h * DQ + gd] = f2bf(o);
    }
}

// ---------------------------------------------------------------------------
// Output projection: Hb(bf16) @ whb(bf16)^T + bias, fp32 store.  Grid (32,8).
// ---------------------------------------------------------------------------
__global__ __launch_bounds__(256) void outproj_mfma(const unsigned short* __restrict__ Hb,
                                                    const unsigned short* __restrict__ whb,
                                                    const float* __restrict__ bias,
                                                    float* __restrict__ C) {
    __shared__ __align__(16) short As[2][64 * 32];
    __shared__ __align__(16) short Bs[2][64 * 32];
    f32x4 acc[2][2];
    const f32x4 zz = {0.f, 0.f, 0.f, 0.f};
#pragma unroll
    for (int i = 0; i < 2; ++i)
#pragma unroll
        for (int j = 0; j < 2; ++j) acc[i][j] = zz;
    const int m0 = blockIdx.x * 64, n0 = blockIdx.y * 64;
    gemm64core(Hb + (size_t)m0 * DM, DM, whb + (size_t)n0 * DM, DM, &As[0][0], &Bs[0][0], acc);
    const int tid = threadIdx.x, wave = tid >> 6, lane = tid & 63;
    const int quad = lane >> 4, l16 = lane & 15;
    const int wr = wave >> 1, wc = wave & 1;
#pragma unroll
    for (int i = 0; i < 2; ++i)
#pragma unroll
        for (int r = 0; r < 4; ++r) {
            const int gm = m0 + wr * 32 + i * 16 + quad * 4 + r;
#pragma unroll
            for (int j = 0; j < 2; ++j) {
                const int gn = n0 + wc * 32 + j * 16 + l16;
                C[(size_t)gm * DM + gn] = acc[i][j][r] + bias[gn];
            }
        }
}

// ---------------------------------------------------------------------------
extern "C" void kernel_launch(void* const* d_in, const int* in_sizes, int n_in,
                              void* d_out, int out_size, void* d_ws, size_t ws_size,
                              hipStream_t stream) {
    const float* q     = (const float*)d_in[0];
    const float* k     = (const float*)d_in[1];
    const float* em    = (const float*)d_in[2];
    const float* pad   = (const float*)d_in[3];
    const float* w_q_w = (const float*)d_in[4];
    const float* w_q_b = (const float*)d_in[5];
    const float* w_k   = (const float*)d_in[6];
    const float* w_v   = (const float*)d_in[7];
    const float* w_h_w = (const float*)d_in[8];
    const float* w_h_b = (const float*)d_in[9];
    const float* b_ks  = (const float*)d_in[10];
    const float* b_vs  = (const float*)d_in[11];

    float* out     = (float*)d_out;                       // (B, LQ, DM) fp32
    float* weights = out + (size_t)NB * LQ * DM;          // (H*B, LQ, LK) fp32

    char* ws = (char*)d_ws;
    unsigned short* qb  = (unsigned short*)(ws + 0);          // 2 MB
    unsigned short* kb  = (unsigned short*)(ws + 2097152);    // 2 MB
    unsigned short* wqb = (unsigned short*)(ws + 4194304);    // 512 KB
    unsigned short* wkb = (unsigned short*)(ws + 4718592);
    unsigned short* wvb = (unsigned short*)(ws + 5242880);
    unsigned short* whb = (unsigned short*)(ws + 5767168);
    unsigned short* Qp  = (unsigned short*)(ws + 6291456);    // 2 MB bf16
    unsigned short* Kp  = (unsigned short*)(ws + 8388608);    // 2 MB bf16
    unsigned short* Vt  = (unsigned short*)(ws + 10485760);   // 2 MB f16 [b][d][k]
    unsigned short* Hb  = (unsigned short*)(ws + 12582912);   // 2 MB bf16
    unsigned short* Pk  = (unsigned short*)(ws + 14680064);   // 2 MB 9-bit packs

    prep_kernel<<<dim3(512, 7), 256, 0, stream>>>(q, k, w_q_w, w_k, w_v, w_h_w,
                                                  em, pad, qb, kb, wqb, wkb, wvb, whb, Pk);
    proj_all<<<dim3(32, 8, 3), 256, 0, stream>>>(qb, kb, wqb, wkb, wvb, w_q_b, Qp, Kp, Vt);
    attn_fused<<<dim3(LQ / QT, 32), 512, 0, stream>>>(Qp, Kp, Vt, Pk, b_ks, b_vs, weights, Hb);
    outproj_mfma<<<dim3(32, 8), 256, 0, stream>>>(Hb, whb, w_h_b, out);
}